// Round 9
// baseline (444.511 us; speedup 1.0000x reference)
//
#include <hip/hip_runtime.h>
#include <hip/hip_fp16.h>

namespace {

constexpr int BATCH = 16;
constexpr int NSP   = 4096;   // 64*64
constexpr int CQKV  = 768;
constexpr float EPS = 1e-15f;

// Channel permutation: permuted row p = cls*256 + g*8 + d  <->  orig = g*24 + cls*8 + d
// (cls: 0=q, 1=k, 2=v; g = attention group 0..31 within its branch)

struct alignas(8) Half4 { __half v[4]; };

typedef _Float16 f16x8 __attribute__((ext_vector_type(8)));
typedef float f32x4 __attribute__((ext_vector_type(4)));

#define MFMA16(a, b, c) __builtin_amdgcn_mfma_f32_16x16x32_f16((a), (b), (c), 0, 0, 0)

__device__ inline void gload16(const void* g, void* l) {
  __builtin_amdgcn_global_load_lds(
      (const __attribute__((address_space(1))) void*)g,
      (__attribute__((address_space(3))) void*)l, 16, 0, 0);
}

// ---------------- pass 0a: x [b][256][4096] f32 -> xtH/xtL [b][4096][256] fp16, pre-swizzled --
__global__ __launch_bounds__(256)
void xprep_kernel(const float* __restrict__ x, _Float16* __restrict__ xh,
                  _Float16* __restrict__ xl) {
  const int b  = blockIdx.z;
  const int c0 = blockIdx.y * 64;
  const int n0 = blockIdx.x * 64;
  __shared__ float T[64][65];
  const int tid = threadIdx.x;
  const int cl  = tid >> 4;
  const int n4  = (tid & 15) * 4;
  const float* xb = x + ((size_t)b * 256 + c0) * NSP + n0;
#pragma unroll
  for (int i = 0; i < 4; ++i) {
    const int c = cl + i * 16;
    float4 v = *(const float4*)&xb[(size_t)c * NSP + n4];
    T[n4 + 0][c] = v.x; T[n4 + 1][c] = v.y; T[n4 + 2][c] = v.z; T[n4 + 3][c] = v.w;
  }
  __syncthreads();
  const int n   = tid >> 2;
  const int cb  = (tid & 3) * 16;
  const int ng  = n0 + n;
  const int swz = (ng >> 1) & 3;
  _Float16 hi[16], lo[16];
#pragma unroll
  for (int j = 0; j < 16; ++j) {
    float v = T[n][cb + j];
    _Float16 h = (_Float16)v;
    hi[j] = h;
    lo[j] = (_Float16)(v - (float)h);
  }
  const int cg  = c0 + cb;
  const int grp = cg >> 5;
  const int b0  = (cg >> 3) & 3;
  const int s0  = b0 ^ swz;
  const int s1  = (b0 + 1) ^ swz;
  _Float16* dh = xh + ((size_t)b * NSP + ng) * 256 + grp * 32;
  _Float16* dl = xl + ((size_t)b * NSP + ng) * 256 + grp * 32;
  *(f16x8*)&dh[s0 * 8] = *(f16x8*)&hi[0];
  *(f16x8*)&dh[s1 * 8] = *(f16x8*)&hi[8];
  *(f16x8*)&dl[s0 * 8] = *(f16x8*)&lo[0];
  *(f16x8*)&dl[s1 * 8] = *(f16x8*)&lo[8];
}

// ---------------- pass 0b: w_qkv split fp16, PERMUTED rows, pre-swizzled ----------------
__global__ __launch_bounds__(256)
void wprep_kernel(const float* __restrict__ w, _Float16* __restrict__ wh,
                  _Float16* __restrict__ wl) {
  const int p    = blockIdx.x;               // permuted row
  const int cls  = p >> 8;
  const int g    = (p & 255) >> 3;
  const int d    = p & 7;
  const int orig = g * 24 + cls * 8 + d;
  const int c    = threadIdx.x;
  float v = w[(size_t)orig * 256 + c];
  _Float16 h = (_Float16)v;
  _Float16 l = (_Float16)(v - (float)h);
  const int swz = (p >> 1) & 3;
  const int pos = (c >> 5) * 32 + (((c >> 3) & 3) ^ swz) * 8 + (c & 7);
  wh[(size_t)p * 256 + pos] = h;
  wl[(size_t)p * 256 + pos] = l;
}

// ---------------- pass 0c: w_proj [256][512] f32 -> fp16, pre-swizzled by o-row --------------
__global__ __launch_bounds__(256)
void wprep2_kernel(const float* __restrict__ w, _Float16* __restrict__ wp) {
  const int o = blockIdx.x;
  const int swz = (o >> 1) & 3;
#pragma unroll
  for (int i = 0; i < 2; ++i) {
    const int c = threadIdx.x + i * 256;
    float v = w[(size_t)o * 512 + c];
    const int pos = (c >> 5) * 32 + (((c >> 3) & 3) ^ swz) * 8 + (c & 7);
    wp[(size_t)o * 512 + pos] = (_Float16)v;
  }
}

// ---------------- pass 1: qkv conv1x1 — split-fp16 MFMA for q rows, plain fp16 for k/v -------
// grid (32, 6, 16); by<2 -> q o-tiles (3 MFMA), by>=2 -> k/v o-tiles (1 MFMA)
__global__ __launch_bounds__(256, 4)
void qkv_mfma_kernel(const _Float16* __restrict__ xh, const _Float16* __restrict__ xl,
                     const _Float16* __restrict__ wh, const _Float16* __restrict__ wl,
                     __half* __restrict__ qkvh) {
  const int b     = blockIdx.z;
  const int by    = blockIdx.y;
  const int oBase = by * 128;
  const int nBase = blockIdx.x * 128;
  const bool SPLIT = (by < 2);
  __shared__ __align__(16) _Float16 S[17408];
  const int tid  = threadIdx.x;
  const int lane = tid & 63;
  const int wid  = tid >> 6;
  const int wo   = (wid >> 1) * 64;
  const int wn   = (wid & 1) * 64;

  f32x4 acc[4][4];
#pragma unroll
  for (int i = 0; i < 4; ++i)
#pragma unroll
    for (int j = 0; j < 4; ++j) acc[i][j] = {0.f, 0.f, 0.f, 0.f};

  const size_t xoff = ((size_t)b * NSP + nBase) * 256;
  const _Float16* lanesrc;
  _Float16* ldst;
  if (SPLIT) {
    // wave wid stages plane wid: 0=AH 1=AL 2=BH 3=BL (128 rows each, 8 loads)
    const _Float16* sb =
        (wid == 0) ? wh + (size_t)oBase * 256 :
        (wid == 1) ? wl + (size_t)oBase * 256 :
        (wid == 2) ? xh + xoff : xl + xoff;
    lanesrc = sb + (size_t)(lane >> 2) * 256 + (lane & 3) * 8;
    ldst = S + wid * 4096;
  } else {
    // planes AH (S[0..4096)) and BH (S[8192..12288)); wave covers 64 rows (4 loads)
    const _Float16* sb = (wid < 2 ? wh + (size_t)oBase * 256 : xh + xoff)
                         + (size_t)(wid & 1) * 64 * 256;
    lanesrc = sb + (size_t)(lane >> 2) * 256 + (lane & 3) * 8;
    ldst = S + (wid >> 1) * 8192 + (wid & 1) * 2048;
  }

  const int fr = lane & 15;
  const int sl = (lane >> 4) ^ ((fr >> 1) & 3);

  for (int t = 0; t < 8; ++t) {
    const _Float16* ls = lanesrc + t * 32;
    if (SPLIT) {
#pragma unroll
      for (int i = 0; i < 8; ++i)
        gload16(ls + (size_t)i * 16 * 256, ldst + i * 512);
    } else {
#pragma unroll
      for (int i = 0; i < 4; ++i)
        gload16(ls + (size_t)i * 16 * 256, ldst + i * 512);
    }
    __syncthreads();

    if (SPLIT) {
      f16x8 bHf[4], bLf[4];
#pragma unroll
      for (int i = 0; i < 4; ++i) {
        bHf[i] = *(const f16x8*)&S[2 * 4096 + (wn + i * 16 + fr) * 32 + sl * 8];
        bLf[i] = *(const f16x8*)&S[3 * 4096 + (wn + i * 16 + fr) * 32 + sl * 8];
      }
#pragma unroll
      for (int mi = 0; mi < 4; ++mi) {
        f16x8 aHf = *(const f16x8*)&S[0 * 4096 + (wo + mi * 16 + fr) * 32 + sl * 8];
        f16x8 aLf = *(const f16x8*)&S[1 * 4096 + (wo + mi * 16 + fr) * 32 + sl * 8];
#pragma unroll
        for (int ni = 0; ni < 4; ++ni) {
          f32x4 a = acc[mi][ni];
          a = MFMA16(aHf, bHf[ni], a);
          a = MFMA16(aHf, bLf[ni], a);
          a = MFMA16(aLf, bHf[ni], a);
          acc[mi][ni] = a;
        }
      }
    } else {
      f16x8 bHf[4];
#pragma unroll
      for (int i = 0; i < 4; ++i)
        bHf[i] = *(const f16x8*)&S[2 * 4096 + (wn + i * 16 + fr) * 32 + sl * 8];
#pragma unroll
      for (int mi = 0; mi < 4; ++mi) {
        f16x8 aHf = *(const f16x8*)&S[0 * 4096 + (wo + mi * 16 + fr) * 32 + sl * 8];
#pragma unroll
        for (int ni = 0; ni < 4; ++ni)
          acc[mi][ni] = MFMA16(aHf, bHf[ni], acc[mi][ni]);
      }
    }
    __syncthreads();
  }

  // epilogue: LDS bounce then coalesced 16B stores (qkvh in PERMUTED layout)
  const int orow = (lane >> 4) * 4;
  const int ncol = lane & 15;
#pragma unroll
  for (int mi = 0; mi < 4; ++mi)
#pragma unroll
    for (int ni = 0; ni < 4; ++ni)
#pragma unroll
      for (int r = 0; r < 4; ++r)
        S[(wo + mi * 16 + orow + r) * 136 + wn + ncol + ni * 16] =
            (_Float16)acc[mi][ni][r];
  __syncthreads();
  _Float16* qk = (_Float16*)qkvh;
#pragma unroll
  for (int j = 0; j < 8; ++j) {
    const int c   = j * 256 + tid;
    const int row = c >> 4;
    const int blk = c & 15;
    *(f16x8*)&qk[((size_t)b * CQKV + oBase + row) * NSP + nBase + blk * 8] =
        *(const f16x8*)&S[row * 136 + blk * 8];
  }
}

// ---------------- pass 2: fused depthwise 5x5 + grouped 8x8 pointwise (permuted rows) --------
__global__ __launch_bounds__(256)
void dwpw_kernel(const __half* __restrict__ qkv, const float* __restrict__ wdw,
                 const float* __restrict__ wpw, __half* __restrict__ agg) {
  const int b  = blockIdx.z;
  const int gp = blockIdx.y;                      // original 8-channel group 0..95
  const int y0 = blockIdx.x * 32;
  const int c0w   = gp * 8;                       // original channel base (weights)
  const int c0dat = (gp % 3) * 256 + (gp / 3) * 8;// permuted row base (data)
  __shared__ __align__(16) _Float16 tile[8 * 36 * 72 + 8];
  const int tid = threadIdx.x;

  {
    f16x8 zz = {};
    for (int i = tid; i < 2593; i += 256)
      *(f16x8*)&tile[i * 8] = zz;
  }
  __syncthreads();

#pragma unroll
  for (int chs = 0; chs < 8; ++chs) {
    const __half* src = qkv + ((size_t)b * CQKV + c0dat + chs) * NSP;
    for (int i = tid; i < 288; i += 256) {
      const int tr = i >> 3, qx = i & 7;
      const int gy = y0 + tr - 2;
      if (gy >= 0 && gy < 64)
        *(f16x8*)&tile[8 + chs * 2592 + tr * 72 + qx * 8] =
            *(const f16x8*)&src[gy * 64 + qx * 8];
    }
  }
  __syncthreads();

  const int tx = tid & 31;
  const int ty = tid >> 5;

  float pwacc[8][4][2];
#pragma unroll
  for (int o = 0; o < 8; ++o)
#pragma unroll
    for (int r = 0; r < 4; ++r) { pwacc[o][r][0] = 0.f; pwacc[o][r][1] = 0.f; }

  typedef _Float16 f16x2 __attribute__((ext_vector_type(2)));
#pragma unroll
  for (int chc = 0; chc < 8; ++chc) {
    const float* wd = wdw + (size_t)(c0w + chc) * 25;
    float dwacc[4][2] = {{0.f, 0.f}, {0.f, 0.f}, {0.f, 0.f}, {0.f, 0.f}};
#pragma unroll
    for (int ir = 0; ir < 8; ++ir) {
      const int base = 8 + chc * 2592 + (4 * ty + ir) * 72 + 2 * tx - 2;
      const f16x2* p = (const f16x2*)&tile[base];
      f16x2 pa = p[0], pb = p[1], pc = p[2];
      float w[6];
      w[0] = (float)pa[0]; w[1] = (float)pa[1];
      w[2] = (float)pb[0]; w[3] = (float)pb[1];
      w[4] = (float)pc[0]; w[5] = (float)pc[1];
#pragma unroll
      for (int o = 0; o < 4; ++o) {
        const int dy = ir - o;
        if (dy >= 0 && dy <= 4) {
#pragma unroll
          for (int dx = 0; dx < 5; ++dx) {
            const float wv = wd[dy * 5 + dx];
            dwacc[o][0] = fmaf(w[dx],     wv, dwacc[o][0]);
            dwacc[o][1] = fmaf(w[dx + 1], wv, dwacc[o][1]);
          }
        }
      }
    }
#pragma unroll
    for (int o = 0; o < 8; ++o) {
      const float pwv = wpw[(size_t)gp * 64 + o * 8 + chc];
#pragma unroll
      for (int r = 0; r < 4; ++r) {
        pwacc[o][r][0] = fmaf(pwv, dwacc[r][0], pwacc[o][r][0]);
        pwacc[o][r][1] = fmaf(pwv, dwacc[r][1], pwacc[o][r][1]);
      }
    }
  }

#pragma unroll
  for (int o = 0; o < 8; ++o) {
#pragma unroll
    for (int r = 0; r < 4; ++r) {
      __half2 hv = __floats2half2_rn(pwacc[o][r][0], pwacc[o][r][1]);
      *(__half2*)&agg[((size_t)b * CQKV + c0dat + o) * NSP + (y0 + 4 * ty + r) * 64 + 2 * tx] = hv;
    }
  }
}

// ---------------- pass 3: KV reduce + att written IN PLACE over the group's v rows ----------
// att[n][e] stored at vrows[n*8 + e]  (v rows are dead after phase 1; only this block reads them)
__global__ __launch_bounds__(256)
void kvatt_kernel(__half* qkvbuf, __half* aggbuf) {
  const int g = blockIdx.x;          // 0..63
  const int b = blockIdx.y;
  __half* buf = (g < 32 ? qkvbuf : aggbuf) + (size_t)b * CQKV * NSP;
  const int gl = g & 31;
  const __half* qsrc = buf + (size_t)(gl * 8) * NSP;
  const __half* ksrc = buf + (size_t)(256 + gl * 8) * NSP;
  __half*       vrow = buf + (size_t)(512 + gl * 8) * NSP;   // v source AND att dest
  const int tid = threadIdx.x;

  float kv[8][9];
#pragma unroll
  for (int d = 0; d < 8; ++d)
#pragma unroll
    for (int e = 0; e < 9; ++e) kv[d][e] = 0.f;

  for (int i = 0; i < 4; ++i) {
    const int n0 = i * 1024 + tid * 4;
    Half4 kh[8], vh[8];
#pragma unroll
    for (int d = 0; d < 8; ++d) kh[d] = *(const Half4*)&ksrc[(size_t)d * NSP + n0];
#pragma unroll
    for (int e = 0; e < 8; ++e) vh[e] = *(const Half4*)&vrow[(size_t)e * NSP + n0];
#pragma unroll
    for (int j = 0; j < 4; ++j) {
      float kk[8], vv[8];
#pragma unroll
      for (int d = 0; d < 8; ++d) kk[d] = fmaxf(__half2float(kh[d].v[j]), 0.f);
#pragma unroll
      for (int e = 0; e < 8; ++e) vv[e] = __half2float(vh[e].v[j]);
#pragma unroll
      for (int d = 0; d < 8; ++d) {
#pragma unroll
        for (int e = 0; e < 8; ++e) kv[d][e] = fmaf(kk[d], vv[e], kv[d][e]);
        kv[d][8] += kk[d];
      }
    }
  }

  __shared__ float red[4][72];
  __shared__ float kvs[72];
  const int lane = tid & 63;
  const int wv   = tid >> 6;
#pragma unroll
  for (int d = 0; d < 8; ++d)
#pragma unroll
    for (int e = 0; e < 9; ++e) {
      float v = kv[d][e];
      v += __shfl_xor(v, 32);
      v += __shfl_xor(v, 16);
      v += __shfl_xor(v, 8);
      v += __shfl_xor(v, 4);
      v += __shfl_xor(v, 2);
      v += __shfl_xor(v, 1);
      kv[d][e] = v;
    }
  if (lane == 0) {
#pragma unroll
    for (int d = 0; d < 8; ++d)
#pragma unroll
      for (int e = 0; e < 9; ++e) red[wv][d * 9 + e] = kv[d][e];
  }
  __syncthreads();
  if (tid < 72) kvs[tid] = red[0][tid] + red[1][tid] + red[2][tid] + red[3][tid];
  __syncthreads();   // ALSO orders all phase-1 v reads before any att write below

  float kvr[8][9];
#pragma unroll
  for (int d = 0; d < 8; ++d)
#pragma unroll
    for (int e = 0; e < 9; ++e) kvr[d][e] = kvs[d * 9 + e];

  // phase 2: att[n][e] = relu(q)·kv / den, written over v rows as [n][8]
  _Float16* dst = (_Float16*)vrow;
  for (int i = 0; i < 4; ++i) {
    const int n0 = i * 1024 + tid * 4;
    Half4 qh[8];
#pragma unroll
    for (int d = 0; d < 8; ++d) qh[d] = *(const Half4*)&qsrc[(size_t)d * NSP + n0];
#pragma unroll
    for (int j = 0; j < 4; ++j) {
      float q[8];
#pragma unroll
      for (int d = 0; d < 8; ++d) q[d] = fmaxf(__half2float(qh[d].v[j]), 0.f);
      float num[9];
#pragma unroll
      for (int e = 0; e < 9; ++e) {
        float s = 0.f;
#pragma unroll
        for (int d = 0; d < 8; ++d) s = fmaf(q[d], kvr[d][e], s);
        num[e] = s;
      }
      const float r = 1.f / (num[8] + EPS);
      f16x8 o8;
#pragma unroll
      for (int e = 0; e < 8; ++e) o8[e] = (_Float16)(num[e] * r);
      *(f16x8*)&dst[(size_t)(n0 + j) * 8] = o8;
    }
  }
}

// ---------------- pass 4: proj GEMM (B = att in v rows) + BN ----------------
__global__ __launch_bounds__(256, 4)
void proj2_kernel(const __half* __restrict__ qkvbuf, const __half* __restrict__ aggbuf,
                  const _Float16* __restrict__ wp, float* __restrict__ out,
                  const float* __restrict__ gamma, const float* __restrict__ beta,
                  const float* __restrict__ mean, const float* __restrict__ var) {
  const int b     = blockIdx.z;
  const int oBase = blockIdx.y * 128;
  const int nBase = blockIdx.x * 128;
  __shared__ __align__(16) _Float16 S[2 * 4096];
  const int tid  = threadIdx.x;
  const int lane = tid & 63;
  const int wid  = tid >> 6;
  const int wo   = (wid >> 1) * 64;
  const int wn   = (wid & 1) * 64;

  f32x4 acc[4][4];
#pragma unroll
  for (int i = 0; i < 4; ++i)
#pragma unroll
    for (int j = 0; j < 4; ++j) acc[i][j] = {0.f, 0.f, 0.f, 0.f};

  const _Float16* wpb  = wp + (size_t)oBase * 512;
  const _Float16* qk_b = (const _Float16*)qkvbuf + (size_t)b * CQKV * NSP;
  const _Float16* ag_b = (const _Float16*)aggbuf + (size_t)b * CQKV * NSP;

  const int fr = lane & 15;
  const int sl = (lane >> 4) ^ ((fr >> 1) & 3);

  for (int t = 0; t < 16; ++t) {
#pragma unroll
    for (int i = 0; i < 2; ++i) {
      const int c  = tid + i * 256;       // chunk 0..511
      const int r  = c >> 2;              // n-local row
      const int cb = c & 3;               // 16B slot
      // A: pre-swizzled source, linear copy
      gload16(wpb + (size_t)r * 512 + t * 32 + cb * 8, &S[c * 8]);
      // B: inverse-swizzle at source; att group g lives in that group's v rows
      const int g = t * 4 + (cb ^ ((c >> 3) & 3));
      const _Float16* vb = (g < 32 ? qk_b : ag_b) + (size_t)(512 + (g & 31) * 8) * NSP;
      gload16(vb + (size_t)(nBase + r) * 8, &S[4096 + c * 8]);
    }
    __syncthreads();

    f16x8 bf[4];
#pragma unroll
    for (int i = 0; i < 4; ++i)
      bf[i] = *(const f16x8*)&S[4096 + (wn + i * 16 + fr) * 32 + sl * 8];
#pragma unroll
    for (int mi = 0; mi < 4; ++mi) {
      f16x8 af = *(const f16x8*)&S[(wo + mi * 16 + fr) * 32 + sl * 8];
#pragma unroll
      for (int ni = 0; ni < 4; ++ni)
        acc[mi][ni] = MFMA16(af, bf[ni], acc[mi][ni]);
    }
    __syncthreads();
  }

  const int orow = (lane >> 4) * 4;
  const int ncol = lane & 15;
#pragma unroll
  for (int mi = 0; mi < 4; ++mi) {
#pragma unroll
    for (int r = 0; r < 4; ++r) {
      const int o = oBase + wo + mi * 16 + orow + r;
      const float inv  = gamma[o] / sqrtf(var[o] + 1e-5f);
      const float bias = beta[o] - mean[o] * inv;
      float* dst = out + ((size_t)b * 256 + o) * NSP + nBase + wn + ncol;
#pragma unroll
      for (int ni = 0; ni < 4; ++ni)
        dst[ni * 16] = acc[mi][ni][r] * inv + bias;
    }
  }
}

}  // namespace

extern "C" void kernel_launch(void* const* d_in, const int* in_sizes, int n_in,
                              void* d_out, int out_size, void* d_ws, size_t ws_size,
                              hipStream_t stream) {
  const float* x      = (const float*)d_in[0];
  const float* w_qkv  = (const float*)d_in[1];
  const float* w_dw   = (const float*)d_in[2];
  const float* w_pw   = (const float*)d_in[3];
  const float* w_proj = (const float*)d_in[4];
  const float* gamma  = (const float*)d_in[5];
  const float* beta   = (const float*)d_in[6];
  const float* mean   = (const float*)d_in[7];
  const float* var    = (const float*)d_in[8];
  float* out = (float*)d_out;

  const size_t nQ = (size_t)BATCH * CQKV * NSP;   // 50,331,648 halfs (96 MiB)
  __half* qkvh = (__half*)d_ws;                   // permuted channel layout
  __half* aggh = qkvh + nQ;                       // permuted channel layout
  _Float16* wp16 = (_Float16*)(aggh + nQ);        // 256 KB (old kvm spot)

  // x/w split planes alias the agg region (dead until dwpw writes it)
  const size_t nX = (size_t)BATCH * NSP * 256;
  _Float16* xtH = (_Float16*)aggh;
  _Float16* xtL = xtH + nX;
  _Float16* wH  = xtL + nX;
  _Float16* wL  = wH + (size_t)CQKV * 256;

  // 0) prep
  xprep_kernel<<<dim3(64, 4, BATCH), 256, 0, stream>>>(x, xtH, xtL);
  wprep_kernel<<<dim3(CQKV), 256, 0, stream>>>(w_qkv, wH, wL);
  wprep2_kernel<<<dim3(256), 256, 0, stream>>>(w_proj, wp16);

  // 1) qkv GEMM: split-fp16 for q rows (by<2), plain fp16 for k/v rows (by>=2)
  qkv_mfma_kernel<<<dim3(NSP / 128, 6, BATCH), 256, 0, stream>>>(
      xtH, xtL, wH, wL, qkvh);

  // 2) dw + grouped pw (permuted rows)
  dwpw_kernel<<<dim3(2, 96, BATCH), 256, 0, stream>>>(qkvh, w_dw, w_pw, aggh);

  // 3) kv reduce + att materialized in place over v rows
  kvatt_kernel<<<dim3(64, BATCH), 256, 0, stream>>>(qkvh, aggh);

  // 4) proj GEMM + BN
  proj2_kernel<<<dim3(NSP / 128, 2, BATCH), 256, 0, stream>>>(
      qkvh, aggh, wp16, out, gamma, beta, mean, var);
}

// Round 10
// 348.543 us; speedup vs baseline: 1.2753x; 1.2753x over previous
//
#include <hip/hip_runtime.h>
#include <hip/hip_fp16.h>

namespace {

constexpr int BATCH = 16;
constexpr int NSP   = 4096;   // 64*64
constexpr int CQKV  = 768;
constexpr float EPS = 1e-15f;

// Channel permutation: permuted row p = cls*256 + g*8 + d  <->  orig = g*24 + cls*8 + d
// (cls: 0=q, 1=k, 2=v; g = attention group 0..31 within its branch)

struct alignas(8) Half4 { __half v[4]; };

typedef _Float16 f16x8 __attribute__((ext_vector_type(8)));
typedef float f32x4 __attribute__((ext_vector_type(4)));

#define MFMA16(a, b, c) __builtin_amdgcn_mfma_f32_16x16x32_f16((a), (b), (c), 0, 0, 0)

__device__ inline void gload16(const void* g, void* l) {
  __builtin_amdgcn_global_load_lds(
      (const __attribute__((address_space(1))) void*)g,
      (__attribute__((address_space(3))) void*)l, 16, 0, 0);
}

// ---------------- pass 0a: x [b][256][4096] f32 -> xtH/xtL [b][4096][256] fp16, pre-swizzled --
__global__ __launch_bounds__(256)
void xprep_kernel(const float* __restrict__ x, _Float16* __restrict__ xh,
                  _Float16* __restrict__ xl) {
  const int b  = blockIdx.z;
  const int c0 = blockIdx.y * 64;
  const int n0 = blockIdx.x * 64;
  __shared__ float T[64][65];
  const int tid = threadIdx.x;
  const int cl  = tid >> 4;
  const int n4  = (tid & 15) * 4;
  const float* xb = x + ((size_t)b * 256 + c0) * NSP + n0;
#pragma unroll
  for (int i = 0; i < 4; ++i) {
    const int c = cl + i * 16;
    float4 v = *(const float4*)&xb[(size_t)c * NSP + n4];
    T[n4 + 0][c] = v.x; T[n4 + 1][c] = v.y; T[n4 + 2][c] = v.z; T[n4 + 3][c] = v.w;
  }
  __syncthreads();
  const int n   = tid >> 2;
  const int cb  = (tid & 3) * 16;
  const int ng  = n0 + n;
  const int swz = (ng >> 1) & 3;
  _Float16 hi[16], lo[16];
#pragma unroll
  for (int j = 0; j < 16; ++j) {
    float v = T[n][cb + j];
    _Float16 h = (_Float16)v;
    hi[j] = h;
    lo[j] = (_Float16)(v - (float)h);
  }
  const int cg  = c0 + cb;
  const int grp = cg >> 5;
  const int b0  = (cg >> 3) & 3;
  const int s0  = b0 ^ swz;
  const int s1  = (b0 + 1) ^ swz;
  _Float16* dh = xh + ((size_t)b * NSP + ng) * 256 + grp * 32;
  _Float16* dl = xl + ((size_t)b * NSP + ng) * 256 + grp * 32;
  *(f16x8*)&dh[s0 * 8] = *(f16x8*)&hi[0];
  *(f16x8*)&dh[s1 * 8] = *(f16x8*)&hi[8];
  *(f16x8*)&dl[s0 * 8] = *(f16x8*)&lo[0];
  *(f16x8*)&dl[s1 * 8] = *(f16x8*)&lo[8];
}

// ---------------- pass 0b: w_qkv split fp16, PERMUTED rows, pre-swizzled ----------------
__global__ __launch_bounds__(256)
void wprep_kernel(const float* __restrict__ w, _Float16* __restrict__ wh,
                  _Float16* __restrict__ wl) {
  const int p    = blockIdx.x;               // permuted row
  const int cls  = p >> 8;
  const int g    = (p & 255) >> 3;
  const int d    = p & 7;
  const int orig = g * 24 + cls * 8 + d;
  const int c    = threadIdx.x;
  float v = w[(size_t)orig * 256 + c];
  _Float16 h = (_Float16)v;
  _Float16 l = (_Float16)(v - (float)h);
  const int swz = (p >> 1) & 3;
  const int pos = (c >> 5) * 32 + (((c >> 3) & 3) ^ swz) * 8 + (c & 7);
  wh[(size_t)p * 256 + pos] = h;
  wl[(size_t)p * 256 + pos] = l;
}

// ---------------- pass 0c: w_proj [256][512] f32 -> fp16, pre-swizzled by o-row --------------
__global__ __launch_bounds__(256)
void wprep2_kernel(const float* __restrict__ w, _Float16* __restrict__ wp) {
  const int o = blockIdx.x;
  const int swz = (o >> 1) & 3;
#pragma unroll
  for (int i = 0; i < 2; ++i) {
    const int c = threadIdx.x + i * 256;
    float v = w[(size_t)o * 512 + c];
    const int pos = (c >> 5) * 32 + (((c >> 3) & 3) ^ swz) * 8 + (c & 7);
    wp[(size_t)o * 512 + pos] = (_Float16)v;
  }
}

// ---------------- pass 1a: q rows (0..255) — split-fp16 MFMA (fp32 accuracy) ----------------
// grid (32, 2, 16); 4 planes AH/AL/BH/BL, wave wid stages plane wid (8 gloads).
__global__ __launch_bounds__(256, 4)
void qkv_split_kernel(const _Float16* __restrict__ xh, const _Float16* __restrict__ xl,
                      const _Float16* __restrict__ wh, const _Float16* __restrict__ wl,
                      __half* __restrict__ qkvh) {
  const int b     = blockIdx.z;
  const int oBase = blockIdx.y * 128;
  const int nBase = blockIdx.x * 128;
  __shared__ __align__(16) _Float16 S[17408];
  const int tid  = threadIdx.x;
  const int lane = tid & 63;
  const int wid  = tid >> 6;
  const int wo   = (wid >> 1) * 64;
  const int wn   = (wid & 1) * 64;

  f32x4 acc[4][4];
#pragma unroll
  for (int i = 0; i < 4; ++i)
#pragma unroll
    for (int j = 0; j < 4; ++j) acc[i][j] = {0.f, 0.f, 0.f, 0.f};

  const size_t xoff = ((size_t)b * NSP + nBase) * 256;
  const _Float16* sb =
      (wid == 0) ? wh + (size_t)oBase * 256 :
      (wid == 1) ? wl + (size_t)oBase * 256 :
      (wid == 2) ? xh + xoff : xl + xoff;
  const _Float16* lanesrc = sb + (size_t)(lane >> 2) * 256 + (lane & 3) * 8;
  _Float16* ldst = S + wid * 4096;

  const int fr = lane & 15;
  const int sl = (lane >> 4) ^ ((fr >> 1) & 3);

  for (int t = 0; t < 8; ++t) {
    const _Float16* ls = lanesrc + t * 32;
#pragma unroll
    for (int i = 0; i < 8; ++i)
      gload16(ls + (size_t)i * 16 * 256, ldst + i * 512);
    __syncthreads();

    f16x8 bHf[4], bLf[4];
#pragma unroll
    for (int i = 0; i < 4; ++i) {
      bHf[i] = *(const f16x8*)&S[2 * 4096 + (wn + i * 16 + fr) * 32 + sl * 8];
      bLf[i] = *(const f16x8*)&S[3 * 4096 + (wn + i * 16 + fr) * 32 + sl * 8];
    }
#pragma unroll
    for (int mi = 0; mi < 4; ++mi) {
      f16x8 aHf = *(const f16x8*)&S[0 * 4096 + (wo + mi * 16 + fr) * 32 + sl * 8];
      f16x8 aLf = *(const f16x8*)&S[1 * 4096 + (wo + mi * 16 + fr) * 32 + sl * 8];
#pragma unroll
      for (int ni = 0; ni < 4; ++ni) {
        f32x4 a = acc[mi][ni];
        a = MFMA16(aHf, bHf[ni], a);
        a = MFMA16(aHf, bLf[ni], a);
        a = MFMA16(aLf, bHf[ni], a);
        acc[mi][ni] = a;
      }
    }
    __syncthreads();
  }

  const int orow = (lane >> 4) * 4;
  const int ncol = lane & 15;
#pragma unroll
  for (int mi = 0; mi < 4; ++mi)
#pragma unroll
    for (int ni = 0; ni < 4; ++ni)
#pragma unroll
      for (int r = 0; r < 4; ++r)
        S[(wo + mi * 16 + orow + r) * 136 + wn + ncol + ni * 16] =
            (_Float16)acc[mi][ni][r];
  __syncthreads();
  _Float16* qk = (_Float16*)qkvh;
#pragma unroll
  for (int j = 0; j < 8; ++j) {
    const int c   = j * 256 + tid;
    const int row = c >> 4;
    const int blk = c & 15;
    *(f16x8*)&qk[((size_t)b * CQKV + oBase + row) * NSP + nBase + blk * 8] =
        *(const f16x8*)&S[row * 136 + blk * 8];
  }
}

// ---------------- pass 1b: k/v rows (256..767) — plain fp16 MFMA ----------------
// grid (32, 4, 16); 2 planes A/B, waves 0/1 stage A halves, 2/3 stage B halves (4 gloads).
__global__ __launch_bounds__(256, 4)
void qkv_plain_kernel(const _Float16* __restrict__ xh, const _Float16* __restrict__ wh,
                      __half* __restrict__ qkvh) {
  const int b     = blockIdx.z;
  const int oBase = 256 + blockIdx.y * 128;
  const int nBase = blockIdx.x * 128;
  __shared__ __align__(16) _Float16 S[17408];
  const int tid  = threadIdx.x;
  const int lane = tid & 63;
  const int wid  = tid >> 6;
  const int wo   = (wid >> 1) * 64;
  const int wn   = (wid & 1) * 64;

  f32x4 acc[4][4];
#pragma unroll
  for (int i = 0; i < 4; ++i)
#pragma unroll
    for (int j = 0; j < 4; ++j) acc[i][j] = {0.f, 0.f, 0.f, 0.f};

  const size_t xoff = ((size_t)b * NSP + nBase) * 256;
  const _Float16* sb = (wid < 2 ? wh + (size_t)oBase * 256 : xh + xoff)
                       + (size_t)(wid & 1) * 64 * 256;
  const _Float16* lanesrc = sb + (size_t)(lane >> 2) * 256 + (lane & 3) * 8;
  _Float16* ldst = S + (wid >> 1) * 4096 + (wid & 1) * 2048;

  const int fr = lane & 15;
  const int sl = (lane >> 4) ^ ((fr >> 1) & 3);

  for (int t = 0; t < 8; ++t) {
    const _Float16* ls = lanesrc + t * 32;
#pragma unroll
    for (int i = 0; i < 4; ++i)
      gload16(ls + (size_t)i * 16 * 256, ldst + i * 512);
    __syncthreads();

    f16x8 bHf[4];
#pragma unroll
    for (int i = 0; i < 4; ++i)
      bHf[i] = *(const f16x8*)&S[4096 + (wn + i * 16 + fr) * 32 + sl * 8];
#pragma unroll
    for (int mi = 0; mi < 4; ++mi) {
      f16x8 aHf = *(const f16x8*)&S[(wo + mi * 16 + fr) * 32 + sl * 8];
#pragma unroll
      for (int ni = 0; ni < 4; ++ni)
        acc[mi][ni] = MFMA16(aHf, bHf[ni], acc[mi][ni]);
    }
    __syncthreads();
  }

  const int orow = (lane >> 4) * 4;
  const int ncol = lane & 15;
#pragma unroll
  for (int mi = 0; mi < 4; ++mi)
#pragma unroll
    for (int ni = 0; ni < 4; ++ni)
#pragma unroll
      for (int r = 0; r < 4; ++r)
        S[(wo + mi * 16 + orow + r) * 136 + wn + ncol + ni * 16] =
            (_Float16)acc[mi][ni][r];
  __syncthreads();
  _Float16* qk = (_Float16*)qkvh;
#pragma unroll
  for (int j = 0; j < 8; ++j) {
    const int c   = j * 256 + tid;
    const int row = c >> 4;
    const int blk = c & 15;
    *(f16x8*)&qk[((size_t)b * CQKV + oBase + row) * NSP + nBase + blk * 8] =
        *(const f16x8*)&S[row * 136 + blk * 8];
  }
}

// ---------------- pass 2: fused depthwise 5x5 + grouped 8x8 pointwise (permuted rows) --------
__global__ __launch_bounds__(256)
void dwpw_kernel(const __half* __restrict__ qkv, const float* __restrict__ wdw,
                 const float* __restrict__ wpw, __half* __restrict__ agg) {
  const int b  = blockIdx.z;
  const int gp = blockIdx.y;                      // original 8-channel group 0..95
  const int y0 = blockIdx.x * 32;
  const int c0w   = gp * 8;                       // original channel base (weights)
  const int c0dat = (gp % 3) * 256 + (gp / 3) * 8;// permuted row base (data)
  __shared__ __align__(16) _Float16 tile[8 * 36 * 72 + 8];
  const int tid = threadIdx.x;

  {
    f16x8 zz = {};
    for (int i = tid; i < 2593; i += 256)
      *(f16x8*)&tile[i * 8] = zz;
  }
  __syncthreads();

#pragma unroll
  for (int chs = 0; chs < 8; ++chs) {
    const __half* src = qkv + ((size_t)b * CQKV + c0dat + chs) * NSP;
    for (int i = tid; i < 288; i += 256) {
      const int tr = i >> 3, qx = i & 7;
      const int gy = y0 + tr - 2;
      if (gy >= 0 && gy < 64)
        *(f16x8*)&tile[8 + chs * 2592 + tr * 72 + qx * 8] =
            *(const f16x8*)&src[gy * 64 + qx * 8];
    }
  }
  __syncthreads();

  const int tx = tid & 31;
  const int ty = tid >> 5;

  float pwacc[8][4][2];
#pragma unroll
  for (int o = 0; o < 8; ++o)
#pragma unroll
    for (int r = 0; r < 4; ++r) { pwacc[o][r][0] = 0.f; pwacc[o][r][1] = 0.f; }

  typedef _Float16 f16x2 __attribute__((ext_vector_type(2)));
#pragma unroll
  for (int chc = 0; chc < 8; ++chc) {
    const float* wd = wdw + (size_t)(c0w + chc) * 25;
    float dwacc[4][2] = {{0.f, 0.f}, {0.f, 0.f}, {0.f, 0.f}, {0.f, 0.f}};
#pragma unroll
    for (int ir = 0; ir < 8; ++ir) {
      const int base = 8 + chc * 2592 + (4 * ty + ir) * 72 + 2 * tx - 2;
      const f16x2* p = (const f16x2*)&tile[base];
      f16x2 pa = p[0], pb = p[1], pc = p[2];
      float w[6];
      w[0] = (float)pa[0]; w[1] = (float)pa[1];
      w[2] = (float)pb[0]; w[3] = (float)pb[1];
      w[4] = (float)pc[0]; w[5] = (float)pc[1];
#pragma unroll
      for (int o = 0; o < 4; ++o) {
        const int dy = ir - o;
        if (dy >= 0 && dy <= 4) {
#pragma unroll
          for (int dx = 0; dx < 5; ++dx) {
            const float wv = wd[dy * 5 + dx];
            dwacc[o][0] = fmaf(w[dx],     wv, dwacc[o][0]);
            dwacc[o][1] = fmaf(w[dx + 1], wv, dwacc[o][1]);
          }
        }
      }
    }
#pragma unroll
    for (int o = 0; o < 8; ++o) {
      const float pwv = wpw[(size_t)gp * 64 + o * 8 + chc];
#pragma unroll
      for (int r = 0; r < 4; ++r) {
        pwacc[o][r][0] = fmaf(pwv, dwacc[r][0], pwacc[o][r][0]);
        pwacc[o][r][1] = fmaf(pwv, dwacc[r][1], pwacc[o][r][1]);
      }
    }
  }

#pragma unroll
  for (int o = 0; o < 8; ++o) {
#pragma unroll
    for (int r = 0; r < 4; ++r) {
      __half2 hv = __floats2half2_rn(pwacc[o][r][0], pwacc[o][r][1]);
      *(__half2*)&agg[((size_t)b * CQKV + c0dat + o) * NSP + (y0 + 4 * ty + r) * 64 + 2 * tx] = hv;
    }
  }
}

// ---------------- pass 3: KV reduce + att written IN PLACE over the group's v rows ----------
__global__ __launch_bounds__(256)
void kvatt_kernel(__half* qkvbuf, __half* aggbuf) {
  const int g = blockIdx.x;          // 0..63
  const int b = blockIdx.y;
  __half* buf = (g < 32 ? qkvbuf : aggbuf) + (size_t)b * CQKV * NSP;
  const int gl = g & 31;
  const __half* qsrc = buf + (size_t)(gl * 8) * NSP;
  const __half* ksrc = buf + (size_t)(256 + gl * 8) * NSP;
  __half*       vrow = buf + (size_t)(512 + gl * 8) * NSP;   // v source AND att dest
  const int tid = threadIdx.x;

  float kv[8][9];
#pragma unroll
  for (int d = 0; d < 8; ++d)
#pragma unroll
    for (int e = 0; e < 9; ++e) kv[d][e] = 0.f;

  for (int i = 0; i < 4; ++i) {
    const int n0 = i * 1024 + tid * 4;
    Half4 kh[8], vh[8];
#pragma unroll
    for (int d = 0; d < 8; ++d) kh[d] = *(const Half4*)&ksrc[(size_t)d * NSP + n0];
#pragma unroll
    for (int e = 0; e < 8; ++e) vh[e] = *(const Half4*)&vrow[(size_t)e * NSP + n0];
#pragma unroll
    for (int j = 0; j < 4; ++j) {
      float kk[8], vv[8];
#pragma unroll
      for (int d = 0; d < 8; ++d) kk[d] = fmaxf(__half2float(kh[d].v[j]), 0.f);
#pragma unroll
      for (int e = 0; e < 8; ++e) vv[e] = __half2float(vh[e].v[j]);
#pragma unroll
      for (int d = 0; d < 8; ++d) {
#pragma unroll
        for (int e = 0; e < 8; ++e) kv[d][e] = fmaf(kk[d], vv[e], kv[d][e]);
        kv[d][8] += kk[d];
      }
    }
  }

  __shared__ float red[4][72];
  __shared__ float kvs[72];
  const int lane = tid & 63;
  const int wv   = tid >> 6;
#pragma unroll
  for (int d = 0; d < 8; ++d)
#pragma unroll
    for (int e = 0; e < 9; ++e) {
      float v = kv[d][e];
      v += __shfl_xor(v, 32);
      v += __shfl_xor(v, 16);
      v += __shfl_xor(v, 8);
      v += __shfl_xor(v, 4);
      v += __shfl_xor(v, 2);
      v += __shfl_xor(v, 1);
      kv[d][e] = v;
    }
  if (lane == 0) {
#pragma unroll
    for (int d = 0; d < 8; ++d)
#pragma unroll
      for (int e = 0; e < 9; ++e) red[wv][d * 9 + e] = kv[d][e];
  }
  __syncthreads();
  if (tid < 72) kvs[tid] = red[0][tid] + red[1][tid] + red[2][tid] + red[3][tid];
  __syncthreads();   // ALSO orders all phase-1 v reads before any att write below

  float kvr[8][9];
#pragma unroll
  for (int d = 0; d < 8; ++d)
#pragma unroll
    for (int e = 0; e < 9; ++e) kvr[d][e] = kvs[d * 9 + e];

  // phase 2: att[n][e] = relu(q)·kv / den, written over v rows as [n][8]
  _Float16* dst = (_Float16*)vrow;
  for (int i = 0; i < 4; ++i) {
    const int n0 = i * 1024 + tid * 4;
    Half4 qh[8];
#pragma unroll
    for (int d = 0; d < 8; ++d) qh[d] = *(const Half4*)&qsrc[(size_t)d * NSP + n0];
#pragma unroll
    for (int j = 0; j < 4; ++j) {
      float q[8];
#pragma unroll
      for (int d = 0; d < 8; ++d) q[d] = fmaxf(__half2float(qh[d].v[j]), 0.f);
      float num[9];
#pragma unroll
      for (int e = 0; e < 9; ++e) {
        float s = 0.f;
#pragma unroll
        for (int d = 0; d < 8; ++d) s = fmaf(q[d], kvr[d][e], s);
        num[e] = s;
      }
      const float r = 1.f / (num[8] + EPS);
      f16x8 o8;
#pragma unroll
      for (int e = 0; e < 8; ++e) o8[e] = (_Float16)(num[e] * r);
      *(f16x8*)&dst[(size_t)(n0 + j) * 8] = o8;
    }
  }
}

// ---------------- pass 4: proj GEMM (B = att in v rows) + BN ----------------
__global__ __launch_bounds__(256, 4)
void proj2_kernel(const __half* __restrict__ qkvbuf, const __half* __restrict__ aggbuf,
                  const _Float16* __restrict__ wp, float* __restrict__ out,
                  const float* __restrict__ gamma, const float* __restrict__ beta,
                  const float* __restrict__ mean, const float* __restrict__ var) {
  const int b     = blockIdx.z;
  const int oBase = blockIdx.y * 128;
  const int nBase = blockIdx.x * 128;
  __shared__ __align__(16) _Float16 S[2 * 4096];
  const int tid  = threadIdx.x;
  const int lane = tid & 63;
  const int wid  = tid >> 6;
  const int wo   = (wid >> 1) * 64;
  const int wn   = (wid & 1) * 64;

  f32x4 acc[4][4];
#pragma unroll
  for (int i = 0; i < 4; ++i)
#pragma unroll
    for (int j = 0; j < 4; ++j) acc[i][j] = {0.f, 0.f, 0.f, 0.f};

  const _Float16* wpb  = wp + (size_t)oBase * 512;
  const _Float16* qk_b = (const _Float16*)qkvbuf + (size_t)b * CQKV * NSP;
  const _Float16* ag_b = (const _Float16*)aggbuf + (size_t)b * CQKV * NSP;

  const int fr = lane & 15;
  const int sl = (lane >> 4) ^ ((fr >> 1) & 3);

  for (int t = 0; t < 16; ++t) {
#pragma unroll
    for (int i = 0; i < 2; ++i) {
      const int c  = tid + i * 256;       // chunk 0..511
      const int r  = c >> 2;              // n-local row
      const int cb = c & 3;               // 16B slot
      // A: pre-swizzled source, linear copy
      gload16(wpb + (size_t)r * 512 + t * 32 + cb * 8, &S[c * 8]);
      // B: inverse-swizzle at source; att group g lives in that group's v rows
      const int g = t * 4 + (cb ^ ((c >> 3) & 3));
      const _Float16* vb = (g < 32 ? qk_b : ag_b) + (size_t)(512 + (g & 31) * 8) * NSP;
      gload16(vb + (size_t)(nBase + r) * 8, &S[4096 + c * 8]);
    }
    __syncthreads();

    f16x8 bf[4];
#pragma unroll
    for (int i = 0; i < 4; ++i)
      bf[i] = *(const f16x8*)&S[4096 + (wn + i * 16 + fr) * 32 + sl * 8];
#pragma unroll
    for (int mi = 0; mi < 4; ++mi) {
      f16x8 af = *(const f16x8*)&S[(wo + mi * 16 + fr) * 32 + sl * 8];
#pragma unroll
      for (int ni = 0; ni < 4; ++ni)
        acc[mi][ni] = MFMA16(af, bf[ni], acc[mi][ni]);
    }
    __syncthreads();
  }

  const int orow = (lane >> 4) * 4;
  const int ncol = lane & 15;
#pragma unroll
  for (int mi = 0; mi < 4; ++mi) {
#pragma unroll
    for (int r = 0; r < 4; ++r) {
      const int o = oBase + wo + mi * 16 + orow + r;
      const float inv  = gamma[o] / sqrtf(var[o] + 1e-5f);
      const float bias = beta[o] - mean[o] * inv;
      float* dst = out + ((size_t)b * 256 + o) * NSP + nBase + wn + ncol;
#pragma unroll
      for (int ni = 0; ni < 4; ++ni)
        dst[ni * 16] = acc[mi][ni][r] * inv + bias;
    }
  }
}

}  // namespace

extern "C" void kernel_launch(void* const* d_in, const int* in_sizes, int n_in,
                              void* d_out, int out_size, void* d_ws, size_t ws_size,
                              hipStream_t stream) {
  const float* x      = (const float*)d_in[0];
  const float* w_qkv  = (const float*)d_in[1];
  const float* w_dw   = (const float*)d_in[2];
  const float* w_pw   = (const float*)d_in[3];
  const float* w_proj = (const float*)d_in[4];
  const float* gamma  = (const float*)d_in[5];
  const float* beta   = (const float*)d_in[6];
  const float* mean   = (const float*)d_in[7];
  const float* var    = (const float*)d_in[8];
  float* out = (float*)d_out;

  const size_t nQ = (size_t)BATCH * CQKV * NSP;   // 50,331,648 halfs (96 MiB)
  __half* qkvh = (__half*)d_ws;                   // permuted channel layout
  __half* aggh = qkvh + nQ;                       // permuted channel layout
  _Float16* wp16 = (_Float16*)(aggh + nQ);        // 256 KB

  // x/w split planes alias the agg region (dead until dwpw writes it)
  const size_t nX = (size_t)BATCH * NSP * 256;
  _Float16* xtH = (_Float16*)aggh;
  _Float16* xtL = xtH + nX;
  _Float16* wH  = xtL + nX;
  _Float16* wL  = wH + (size_t)CQKV * 256;

  // 0) prep
  xprep_kernel<<<dim3(64, 4, BATCH), 256, 0, stream>>>(x, xtH, xtL);
  wprep_kernel<<<dim3(CQKV), 256, 0, stream>>>(w_qkv, wH, wL);
  wprep2_kernel<<<dim3(256), 256, 0, stream>>>(w_proj, wp16);

  // 1a) q rows: split-fp16 (fp32-grade, needed for the near-zero-q ratio)
  qkv_split_kernel<<<dim3(NSP / 128, 2, BATCH), 256, 0, stream>>>(
      xtH, xtL, wH, wL, qkvh);
  // 1b) k/v rows: plain fp16 (relative accuracy suffices)
  qkv_plain_kernel<<<dim3(NSP / 128, 4, BATCH), 256, 0, stream>>>(xtH, wH, qkvh);

  // 2) dw + grouped pw (permuted rows)
  dwpw_kernel<<<dim3(2, 96, BATCH), 256, 0, stream>>>(qkvh, w_dw, w_pw, aggh);

  // 3) kv reduce + att materialized in place over v rows
  kvatt_kernel<<<dim3(64, BATCH), 256, 0, stream>>>(qkvh, aggh);

  // 4) proj GEMM + BN
  proj2_kernel<<<dim3(NSP / 128, 2, BATCH), 256, 0, stream>>>(
      qkvh, aggh, wp16, out, gamma, beta, mean, var);
}